// Round 5
// baseline (148.100 us; speedup 1.0000x reference)
//
#include <hip/hip_runtime.h>

typedef _Float16 half2v __attribute__((ext_vector_type(2)));
typedef _Float16 half8  __attribute__((ext_vector_type(8)));
typedef float    floatx4 __attribute__((ext_vector_type(4)));

#define M_DIM 64
#define K_DIM 8192
#define N_DIM 8192
#define NT 64
#define KSB 4
#define CHUNK (K_DIM / (KSB * 4))   // 512 k-rows per wave
#define STEPS (CHUNK / 32)          // 16 MFMA K-steps per wave

// x fp32 [64][8192] -> xp fp16 tiled [k/32][mt:4][q:4][c:16][j:8]
// so each A-fragment load in mm is one contiguous 1KB wave read.
// j-order within each 8 is sigma=(0,4,1,5,2,6,3,7) matching B nibble unpack.
__global__ __launch_bounds__(256) void permute_x_kernel(
        const float* __restrict__ x, _Float16* __restrict__ xp) {
    const int t  = blockIdx.x * 256 + threadIdx.x;  // 65536 threads
    const int c  = t & 15;
    const int q  = (t >> 4) & 3;
    const int mt = (t >> 6) & 3;
    const int kb = t >> 8;                          // k/32 block, 0..255
    const int m  = mt * 16 + c;
    const int k0 = kb * 32 + q * 8;
    const float* src = x + (size_t)m * K_DIM + k0;
    float4 a = *(const float4*)(src);
    float4 b = *(const float4*)(src + 4);
    union { _Float16 h[8]; float4 f; } u;
    u.h[0] = (_Float16)a.x; u.h[1] = (_Float16)b.x;
    u.h[2] = (_Float16)a.y; u.h[3] = (_Float16)b.y;
    u.h[4] = (_Float16)a.z; u.h[5] = (_Float16)b.z;
    u.h[6] = (_Float16)a.w; u.h[7] = (_Float16)b.w;
    *(float4*)(xp + (size_t)t * 8) = u.f;
}

__device__ __forceinline__ half2v dq_pair(unsigned int bits, half2v sub, half2v sc) {
    union { unsigned int u; half2v h; } cv;
    cv.u = bits;
    return (cv.h - sub) * sc;      // v_pk_add_f16 + v_pk_mul_f16
}

__global__ __launch_bounds__(256, 2) void machete_mm_kernel(
        const _Float16* __restrict__ xp,
        const unsigned int* __restrict__ Bq,
        const float* __restrict__ s,
        float* __restrict__ partial) {
    __shared__ float red[4][32][65];                 // 32.5 KB, padded stride

    const int tid  = threadIdx.x;
    const int w    = tid >> 6;                       // wave 0..3 (splits K)
    const int lane = tid & 63;
    const int c    = lane & 15;                      // mfma col within tile
    const int q    = lane >> 4;
    const int n0   = blockIdx.x * NT;
    const int ci   = blockIdx.y * 4 + w;             // k-chunk 0..15
    const int kb   = ci * CHUNK;
    const int ncol = n0 + 4 * c;

    floatx4 acc[4][4];
    #pragma unroll
    for (int i = 0; i < 4; ++i)
        #pragma unroll
        for (int j = 0; j < 4; ++j) acc[i][j] = (floatx4)0.0f;

    // 4 scale groups per 512-k chunk
    const half2v c1032 = { (_Float16)1032.0f, (_Float16)1032.0f };
    half2v s2g[4][4];
    #pragma unroll
    for (int g = 0; g < 4; ++g) {
        const float4 s4 = *(const float4*)(s + (size_t)((kb >> 7) + g) * N_DIM + ncol);
        s2g[g][0] = (half2v){ (_Float16)s4.x, (_Float16)s4.x };
        s2g[g][1] = (half2v){ (_Float16)s4.y, (_Float16)s4.y };
        s2g[g][2] = (half2v){ (_Float16)s4.z, (_Float16)s4.z };
        s2g[g][3] = (half2v){ (_Float16)s4.w, (_Float16)s4.w };
    }

    const unsigned int* bq = Bq + (size_t)((kb >> 3) + q) * N_DIM + ncol;
    const _Float16*     ap = xp + (size_t)(kb >> 5) * 2048 + lane * 8;

    // Pipeline: B depth-4 (HBM first-touch ~900cyc), A depth-1 (L2-resident).
    uint4 bbuf[4];
    half8 abuf[2][4];
    #pragma unroll
    for (int d = 0; d < 4; ++d) {
        bbuf[d] = *(const uint4*)bq;
        bq += (size_t)4 * N_DIM;
    }
    #pragma unroll
    for (int mt = 0; mt < 4; ++mt)
        abuf[0][mt] = *(const half8*)(ap + mt * 512);

    #pragma unroll 4
    for (int st = 0; st < STEPS; ++st) {
        const int p = st & 1;
        const int g = st >> 2;

        // Unpack B for this step FIRST (frees bbuf[st&3] for the refill).
        union { uint4 v; unsigned int a[4]; } bv;
        bv.v = bbuf[st & 3];
        half8 bf[4];
        #pragma unroll
        for (int t = 0; t < 4; ++t) {
            const unsigned int wd = bv.a[t];
            const half2v sc = s2g[g][t];
            union { half2v h2[4]; half8 h8; } b8;
            b8.h2[0] = dq_pair(( wd        & 0x000F000Fu) | 0x64006400u, c1032, sc);
            b8.h2[1] = dq_pair(((wd >> 4)  & 0x000F000Fu) | 0x64006400u, c1032, sc);
            b8.h2[2] = dq_pair(((wd >> 8)  & 0x000F000Fu) | 0x64006400u, c1032, sc);
            b8.h2[3] = dq_pair(((wd >> 12) & 0x000F000Fu) | 0x64006400u, c1032, sc);
            bf[t] = b8.h8;
        }

        if (st < STEPS - 4) bbuf[st & 3] = *(const uint4*)bq;  // B for st+4
        bq += (size_t)4 * N_DIM;
        if (st < STEPS - 1) {                                  // A for st+1
            ap += 2048;
            #pragma unroll
            for (int mt = 0; mt < 4; ++mt)
                abuf[p ^ 1][mt] = *(const half8*)(ap + mt * 512);
        }

        #pragma unroll
        for (int t = 0; t < 4; ++t)
            #pragma unroll
            for (int mt = 0; mt < 4; ++mt)
                acc[mt][t] = __builtin_amdgcn_mfma_f32_16x16x32_f16(
                    abuf[p][mt], bf[t], acc[mt][t], 0, 0, 0);
    }

    // Cross-wave K reduction in LDS (two rounds of 32 m-rows), then one
    // coalesced fp32 partial-tile store per block. No atomics.
    float* ptile = partial + ((size_t)blockIdx.y * M_DIM) * N_DIM + n0;
    #pragma unroll
    for (int r = 0; r < 2; ++r) {
        if (r) __syncthreads();
        #pragma unroll
        for (int h = 0; h < 2; ++h) {
            const int mt = 2 * r + h;
            #pragma unroll
            for (int t = 0; t < 4; ++t)
                #pragma unroll
                for (int rr = 0; rr < 4; ++rr)
                    red[w][h * 16 + q * 4 + rr][4 * c + t] = acc[mt][t][rr];
        }
        __syncthreads();
        #pragma unroll
        for (int i = 0; i < 8; ++i) {
            const int idx = i * 256 + tid;
            const int mr  = idx >> 6;
            const int nl  = idx & 63;
            const float v = red[0][mr][nl] + red[1][mr][nl]
                          + red[2][mr][nl] + red[3][mr][nl];
            ptile[(size_t)(r * 32 + mr) * N_DIM + nl] = v;
        }
    }
}

__global__ __launch_bounds__(256) void reduce_kernel(
        const float* __restrict__ partial, float* __restrict__ out) {
    const size_t i = ((size_t)blockIdx.x * 256 + threadIdx.x) * 4;
    const size_t S = (size_t)M_DIM * N_DIM;
    float4 v = *(const float4*)(partial + i);
    #pragma unroll
    for (int bk = 1; bk < KSB; ++bk) {
        const float4 u = *(const float4*)(partial + bk * S + i);
        v.x += u.x; v.y += u.y; v.z += u.z; v.w += u.w;
    }
    *(float4*)(out + i) = v;
}

extern "C" void kernel_launch(void* const* d_in, const int* in_sizes, int n_in,
                              void* d_out, int out_size, void* d_ws, size_t ws_size,
                              hipStream_t stream) {
    const float*        x  = (const float*)d_in[0];
    const unsigned int* Bq = (const unsigned int*)d_in[1];
    const float*        sc = (const float*)d_in[2];
    float* out     = (float*)d_out;
    _Float16* xp   = (_Float16*)d_ws;                        // 1 MB
    float* partial = (float*)((char*)d_ws + (1 << 20));      // KSB*2MB = 8 MB

    permute_x_kernel<<<dim3(M_DIM * K_DIM / 8 / 256), 256, 0, stream>>>(x, xp);
    // MEASUREMENT PROBE (this round only): mm launched 3x. Idempotent —
    // reads xp/Bq/s, rewrites identical partial values; same work every call.
    // dur_r5 - dur_r4 = 2 * (T_mm + node_gap) resolves whether mm is the
    // ~30us sink (H2) or the harness reset floor dominates (H1).
    machete_mm_kernel<<<dim3(N_DIM / NT, KSB), 256, 0, stream>>>(xp, Bq, sc, partial);
    machete_mm_kernel<<<dim3(N_DIM / NT, KSB), 256, 0, stream>>>(xp, Bq, sc, partial);
    machete_mm_kernel<<<dim3(N_DIM / NT, KSB), 256, 0, stream>>>(xp, Bq, sc, partial);
    reduce_kernel<<<dim3(M_DIM * N_DIM / (256 * 4)), 256, 0, stream>>>(partial, out);
}

// Round 6
// 98.888 us; speedup vs baseline: 1.4976x; 1.4976x over previous
//
#include <hip/hip_runtime.h>

typedef _Float16 half2v __attribute__((ext_vector_type(2)));
typedef _Float16 half8  __attribute__((ext_vector_type(8)));
typedef float    floatx4 __attribute__((ext_vector_type(4)));

#define M_DIM 64
#define K_DIM 8192
#define N_DIM 8192
#define NT 64
#define KSB 8
#define STAGES 8            // per block: 8 stages x 128 k-rows = 1024 k-rows
// LDS stage buffer: A 16 KB (64m x 128k fp16, frag-tiled) + B 4 KB (16 packed rows x 64 cols)

// x fp32 [64][8192] -> xp fp16 tiled [k/32][mt:4][q:4][c:16][j:8]
// j-order within each 8 is sigma=(0,4,1,5,2,6,3,7) matching B nibble unpack.
// This layout is contiguous in the exact lane order mm's DMA needs.
__global__ __launch_bounds__(256) void permute_x_kernel(
        const float* __restrict__ x, _Float16* __restrict__ xp) {
    const int t  = blockIdx.x * 256 + threadIdx.x;
    const int c  = t & 15;
    const int q  = (t >> 4) & 3;
    const int mt = (t >> 6) & 3;
    const int kb = t >> 8;
    const int m  = mt * 16 + c;
    const int k0 = kb * 32 + q * 8;
    const float* src = x + (size_t)m * K_DIM + k0;
    float4 a = *(const float4*)(src);
    float4 b = *(const float4*)(src + 4);
    union { _Float16 h[8]; float4 f; } u;
    u.h[0] = (_Float16)a.x; u.h[1] = (_Float16)b.x;
    u.h[2] = (_Float16)a.y; u.h[3] = (_Float16)b.y;
    u.h[4] = (_Float16)a.z; u.h[5] = (_Float16)b.z;
    u.h[6] = (_Float16)a.w; u.h[7] = (_Float16)b.w;
    *(float4*)(xp + (size_t)t * 8) = u.f;
}

__device__ __forceinline__ void dma16(const void* g, void* l) {
    // async global->LDS, 16B per lane; LDS dest = wave-uniform base + lane*16
    __builtin_amdgcn_global_load_lds(
        (const __attribute__((address_space(1))) unsigned int*)(uintptr_t)g,
        (__attribute__((address_space(3))) unsigned int*)(uintptr_t)l,
        16, 0, 0);
}

__device__ __forceinline__ half2v dq_pair(unsigned int bits, half2v sub, half2v sc) {
    union { unsigned int u; half2v h; } cv;
    cv.u = bits;
    return (cv.h - sub) * sc;      // v_pk_add_f16 + v_pk_mul_f16
}

__global__ __launch_bounds__(256, 3) void machete_mm_kernel(
        const _Float16* __restrict__ xp,
        const unsigned int* __restrict__ Bq,
        const float* __restrict__ s,
        float* __restrict__ partial) {
    union SM {
        char stage[2][20480];       // [A 16384 | B 4096] double-buffered
        float red[4][32][65];       // epilogue cross-wave reduce (reuse)
    };
    __shared__ SM sm;

    const int tid  = threadIdx.x;
    const int w    = tid >> 6;                       // wave: k-quarter of stage
    const int lane = tid & 63;
    const int c    = lane & 15;
    const int q    = lane >> 4;
    const int n0   = blockIdx.x * NT;
    const int kb0  = blockIdx.y * (K_DIM / KSB);     // 1024-aligned
    const int ncol = n0 + 4 * c;

    const char* a_base = (const char*)xp + (size_t)(kb0 >> 5) * 4096;
    const char* b_base = (const char*)Bq + ((size_t)(kb0 >> 3) * N_DIM + n0) * 4;
    const size_t b_lane = (size_t)(lane >> 4) * ((size_t)N_DIM * 4) + (size_t)(lane & 15) * 16;
    const int    a_lane = lane * 16;

    floatx4 acc[4][4];
    #pragma unroll
    for (int i = 0; i < 4; ++i)
        #pragma unroll
        for (int j = 0; j < 4; ++j) acc[i][j] = (floatx4)0.0f;

    const half2v c1032 = { (_Float16)1032.0f, (_Float16)1032.0f };

    // ---- stage DMA: A 16KB (4 calls/wave) + B 4KB (1 call/wave) ----
    auto stage_dma = [&](int si, int p) {
        const char* as = a_base + (size_t)si * 16384;
        #pragma unroll
        for (int call = 0; call < 4; ++call) {
            const int idx = call * 4 + w;            // 1KB chunk, linear copy
            dma16(as + idx * 1024 + a_lane, &sm.stage[p][idx * 1024]);
        }
        // wave w stages its own packed rows w*4..w*4+3 (its k-quarter)
        const char* bs = b_base + (size_t)(si * 16 + w * 4) * ((size_t)N_DIM * 4) + b_lane;
        dma16(bs, &sm.stage[p][16384 + w * 1024]);
    };

    stage_dma(0, 0);
    __syncthreads();                                 // drains vmcnt(0)

    for (int st = 0; st < STAGES; ++st) {
        const int p = st & 1;

        // Scales FIRST (before next-stage DMA) so waiting on them doesn't
        // drain the freshly-issued DMA queue (vmcnt is in-order/FIFO).
        const float4 s4 = *(const float4*)(s + (size_t)((kb0 >> 7) + st) * N_DIM + ncol);

        if (st + 1 < STAGES) stage_dma(st + 1, p ^ 1);

        half2v s2[4];
        s2[0] = (half2v){ (_Float16)s4.x, (_Float16)s4.x };
        s2[1] = (half2v){ (_Float16)s4.y, (_Float16)s4.y };
        s2[2] = (half2v){ (_Float16)s4.z, (_Float16)s4.z };
        s2[3] = (half2v){ (_Float16)s4.w, (_Float16)s4.w };

        // wave's A frags: k32-block w of this stage
        const char* ab = &sm.stage[p][w * 4096];
        half8 afr[4];
        #pragma unroll
        for (int mt = 0; mt < 4; ++mt)
            afr[mt] = *(const half8*)(ab + mt * 1024 + a_lane);
        // wave's B words: row q of its 4 staged rows, cols 4c..4c+3
        union { uint4 v; unsigned int a[4]; } bv;
        bv.v = *(const uint4*)(&sm.stage[p][16384 + w * 1024 + q * 256 + c * 16]);

        #pragma unroll
        for (int t = 0; t < 4; ++t) {
            const unsigned int wd = bv.a[t];
            const half2v sc = s2[t];
            union { half2v h2[4]; half8 h8; } b8;
            b8.h2[0] = dq_pair(( wd        & 0x000F000Fu) | 0x64006400u, c1032, sc);
            b8.h2[1] = dq_pair(((wd >> 4)  & 0x000F000Fu) | 0x64006400u, c1032, sc);
            b8.h2[2] = dq_pair(((wd >> 8)  & 0x000F000Fu) | 0x64006400u, c1032, sc);
            b8.h2[3] = dq_pair(((wd >> 12) & 0x000F000Fu) | 0x64006400u, c1032, sc);
            #pragma unroll
            for (int mt = 0; mt < 4; ++mt)
                acc[mt][t] = __builtin_amdgcn_mfma_f32_16x16x32_f16(
                    afr[mt], b8.h8, acc[mt][t], 0, 0, 0);
        }

        __syncthreads();   // next-stage DMA complete; all waves done with buf[p]
    }

    // Cross-wave (k-split) reduction in LDS, then coalesced partial store.
    float* ptile = partial + ((size_t)blockIdx.y * M_DIM) * N_DIM + n0;
    #pragma unroll
    for (int r = 0; r < 2; ++r) {
        if (r) __syncthreads();
        #pragma unroll
        for (int h = 0; h < 2; ++h) {
            const int mt = 2 * r + h;
            #pragma unroll
            for (int t = 0; t < 4; ++t)
                #pragma unroll
                for (int rr = 0; rr < 4; ++rr)
                    sm.red[w][h * 16 + q * 4 + rr][4 * c + t] = acc[mt][t][rr];
        }
        __syncthreads();
        #pragma unroll
        for (int i = 0; i < 8; ++i) {
            const int idx = i * 256 + tid;
            const int mr  = idx >> 6;
            const int nl  = idx & 63;
            const float v = sm.red[0][mr][nl] + sm.red[1][mr][nl]
                          + sm.red[2][mr][nl] + sm.red[3][mr][nl];
            ptile[(size_t)(r * 32 + mr) * N_DIM + nl] = v;
        }
    }
}

__global__ __launch_bounds__(256) void reduce_kernel(
        const float* __restrict__ partial, float* __restrict__ out) {
    const size_t i = ((size_t)blockIdx.x * 256 + threadIdx.x) * 4;
    const size_t S = (size_t)M_DIM * N_DIM;
    float4 v = *(const float4*)(partial + i);
    #pragma unroll
    for (int bk = 1; bk < KSB; ++bk) {
        const float4 u = *(const float4*)(partial + bk * S + i);
        v.x += u.x; v.y += u.y; v.z += u.z; v.w += u.w;
    }
    *(float4*)(out + i) = v;
}

extern "C" void kernel_launch(void* const* d_in, const int* in_sizes, int n_in,
                              void* d_out, int out_size, void* d_ws, size_t ws_size,
                              hipStream_t stream) {
    const float*        x  = (const float*)d_in[0];
    const unsigned int* Bq = (const unsigned int*)d_in[1];
    const float*        sc = (const float*)d_in[2];
    float* out     = (float*)d_out;
    _Float16* xp   = (_Float16*)d_ws;                        // 1 MB
    float* partial = (float*)((char*)d_ws + (1 << 20));      // KSB*2MB = 16 MB

    permute_x_kernel<<<dim3(M_DIM * K_DIM / 8 / 256), 256, 0, stream>>>(x, xp);
    machete_mm_kernel<<<dim3(N_DIM / NT, KSB), 256, 0, stream>>>(xp, Bq, sc, partial);
    reduce_kernel<<<dim3(M_DIM * N_DIM / (256 * 4)), 256, 0, stream>>>(partial, out);
}

// Round 7
// 96.046 us; speedup vs baseline: 1.5420x; 1.0296x over previous
//
#include <hip/hip_runtime.h>

typedef _Float16 half2v __attribute__((ext_vector_type(2)));
typedef _Float16 half8  __attribute__((ext_vector_type(8)));
typedef float    floatx4 __attribute__((ext_vector_type(4)));

#define M_DIM 64
#define K_DIM 8192
#define N_DIM 8192
#define NT 512              // cols per block (16 waves x 32 cols)
#define KSB 16              // k-chunks; chunk = 512 k = 4 stages x 128 k
// grid = (8192/NT=16) x KSB=16 = 256 blocks x 1024 thr = exactly 1 block/CU.
// Total traffic: A 16MB + B 32MB + s 2MB + partial(fp16) 16W+16R + out 2
//  = ~84 MB vs ~180 MB for the NT=64 designs (r1-r6, all ~22us at ~7.5TB/s).

// x fp32 [64][8192] -> xp fp16 tiled [k/32][mt:4][lane:64][j:8]
// j-order within each 8 is sigma=(0,4,1,5,2,6,3,7) matching B nibble unpack.
__global__ __launch_bounds__(256) void permute_x_kernel(
        const float* __restrict__ x, _Float16* __restrict__ xp) {
    const int t  = blockIdx.x * 256 + threadIdx.x;
    const int c  = t & 15;
    const int q  = (t >> 4) & 3;
    const int mt = (t >> 6) & 3;
    const int kb = t >> 8;
    const int m  = mt * 16 + c;
    const int k0 = kb * 32 + q * 8;
    const float* src = x + (size_t)m * K_DIM + k0;
    float4 a = *(const float4*)(src);
    float4 b = *(const float4*)(src + 4);
    union { _Float16 h[8]; float4 f; } u;
    u.h[0] = (_Float16)a.x; u.h[1] = (_Float16)b.x;
    u.h[2] = (_Float16)a.y; u.h[3] = (_Float16)b.y;
    u.h[4] = (_Float16)a.z; u.h[5] = (_Float16)b.z;
    u.h[6] = (_Float16)a.w; u.h[7] = (_Float16)b.w;
    *(float4*)(xp + (size_t)t * 8) = u.f;
}

__device__ __forceinline__ void dma16(const void* g, void* l) {
    __builtin_amdgcn_global_load_lds(
        (const __attribute__((address_space(1))) unsigned int*)(uintptr_t)g,
        (__attribute__((address_space(3))) unsigned int*)(uintptr_t)l,
        16, 0, 0);
}

__device__ __forceinline__ half2v dq_pair(unsigned int bits, half2v sub, half2v sc) {
    union { unsigned int u; half2v h; } cv;
    cv.u = bits;
    return (cv.h - sub) * sc;      // v_pk_add_f16 + v_pk_mul_f16
}

__global__ __launch_bounds__(1024, 4) void machete_mm_kernel(
        const _Float16* __restrict__ xp,
        const unsigned int* __restrict__ Bq,
        const float* __restrict__ s,
        _Float16* __restrict__ partial) {
    __shared__ char astage[2][16384];                // A stage dbuf, 32 KB

    const int tid  = threadIdx.x;
    const int w    = tid >> 6;                       // wave 0..15, n-split
    const int lane = tid & 63;
    const int c    = lane & 15;
    const int q    = lane >> 4;
    const int ns   = blockIdx.x;                     // n-strip 0..15
    const int kb   = blockIdx.y;                     // k-chunk 0..15
    const int wc   = ns * NT + w * 32;               // wave's 32-col base

    // Scales: 4 groups (group == stage), 2 col-tiles per wave
    half2v s2[4][2];
    #pragma unroll
    for (int g = 0; g < 4; ++g) {
        const float f0 = s[(size_t)(kb * 4 + g) * N_DIM + wc + c];
        const float f1 = s[(size_t)(kb * 4 + g) * N_DIM + wc + 16 + c];
        s2[g][0] = (half2v){ (_Float16)f0, (_Float16)f0 };
        s2[g][1] = (half2v){ (_Float16)f1, (_Float16)f1 };
    }
    const half2v c1032 = { (_Float16)1032.0f, (_Float16)1032.0f };

    // A: xp chunk for kb = 64 KB; stage = 16 KB (128 k x 64 m, frag-tiled)
    const char* a_base = (const char*)xp + (size_t)kb * 65536;
    // B: packed rows kb*64 .. kb*64+63
    const unsigned int* b_base = Bq + (size_t)(kb * 64) * N_DIM + wc + c;

    auto bload = [&](int st, int d, int t) {
        return b_base[(size_t)(st * 16 + d * 4 + q) * N_DIM + 16 * t];
    };
    auto stage_dma = [&](int st, int p) {            // wave w copies its 1KB
        dma16(a_base + (size_t)st * 16384 + w * 1024 + lane * 16,
              &astage[p][w * 1024]);
    };

    floatx4 acc[4][2];
    #pragma unroll
    for (int i = 0; i < 4; ++i) { acc[i][0] = (floatx4)0.0f; acc[i][1] = (floatx4)0.0f; }

    unsigned int bcur[2][4], bnxt[2][4];
    #pragma unroll
    for (int d = 0; d < 4; ++d) { bcur[0][d] = bload(0, d, 0); bcur[1][d] = bload(0, d, 1); }
    stage_dma(0, 0);
    __syncthreads();                                 // drains DMA(0)

    #pragma unroll
    for (int st = 0; st < 4; ++st) {                 // stages of 128 k
        const int p = st & 1;
        if (st < 3) {
            #pragma unroll
            for (int d = 0; d < 4; ++d) {
                bnxt[0][d] = bload(st + 1, d, 0);
                bnxt[1][d] = bload(st + 1, d, 1);
            }
            stage_dma(st + 1, p ^ 1);
        }

        #pragma unroll
        for (int d = 0; d < 4; ++d) {                // k32 steps in stage
            half8 afr[4];
            #pragma unroll
            for (int mt = 0; mt < 4; ++mt)
                afr[mt] = *(const half8*)(&astage[p][(d * 4 + mt) * 1024 + lane * 16]);
            #pragma unroll
            for (int t = 0; t < 2; ++t) {
                const unsigned int wd = bcur[t][d];
                const half2v sc = s2[st][t];
                union { half2v h2[4]; half8 h8; } b8;
                b8.h2[0] = dq_pair(( wd        & 0x000F000Fu) | 0x64006400u, c1032, sc);
                b8.h2[1] = dq_pair(((wd >> 4)  & 0x000F000Fu) | 0x64006400u, c1032, sc);
                b8.h2[2] = dq_pair(((wd >> 8)  & 0x000F000Fu) | 0x64006400u, c1032, sc);
                b8.h2[3] = dq_pair(((wd >> 12) & 0x000F000Fu) | 0x64006400u, c1032, sc);
                #pragma unroll
                for (int mt = 0; mt < 4; ++mt)
                    acc[mt][t] = __builtin_amdgcn_mfma_f32_16x16x32_f16(
                        afr[mt], b8.h8, acc[mt][t], 0, 0, 0);
            }
        }
        __syncthreads();                             // DMA(st+1) complete
        #pragma unroll
        for (int d = 0; d < 4; ++d) { bcur[0][d] = bnxt[0][d]; bcur[1][d] = bnxt[1][d]; }
    }

    // Epilogue: wave owns (64 m x 32 cols) exclusively -> direct fp16 store.
    _Float16* pt = partial + (size_t)(kb * M_DIM) * N_DIM;
    #pragma unroll
    for (int mt = 0; mt < 4; ++mt)
        #pragma unroll
        for (int t = 0; t < 2; ++t)
            #pragma unroll
            for (int r = 0; r < 4; ++r) {
                const int m = mt * 16 + q * 4 + r;
                pt[(size_t)m * N_DIM + wc + 16 * t + c] = (_Float16)acc[mt][t][r];
            }
}

__global__ __launch_bounds__(256) void reduce_kernel(
        const _Float16* __restrict__ partial, float* __restrict__ out) {
    const size_t i = ((size_t)blockIdx.x * 256 + threadIdx.x) * 8;
    const size_t S = (size_t)M_DIM * N_DIM;
    float a[8] = {0, 0, 0, 0, 0, 0, 0, 0};
    #pragma unroll
    for (int bk = 0; bk < KSB; ++bk) {
        const half8 hv = *(const half8*)(partial + bk * S + i);
        #pragma unroll
        for (int j = 0; j < 8; ++j) a[j] += (float)hv[j];
    }
    float4 v0 = { a[0], a[1], a[2], a[3] };
    float4 v1 = { a[4], a[5], a[6], a[7] };
    *(float4*)(out + i)     = v0;
    *(float4*)(out + i + 4) = v1;
}

extern "C" void kernel_launch(void* const* d_in, const int* in_sizes, int n_in,
                              void* d_out, int out_size, void* d_ws, size_t ws_size,
                              hipStream_t stream) {
    const float*        x  = (const float*)d_in[0];
    const unsigned int* Bq = (const unsigned int*)d_in[1];
    const float*        sc = (const float*)d_in[2];
    float* out        = (float*)d_out;
    _Float16* xp      = (_Float16*)d_ws;                     // 1 MB
    _Float16* partial = (_Float16*)((char*)d_ws + (1 << 20)); // KSB*1MB = 16 MB

    permute_x_kernel<<<dim3(M_DIM * K_DIM / 8 / 256), 256, 0, stream>>>(x, xp);
    machete_mm_kernel<<<dim3(N_DIM / NT, KSB), 1024, 0, stream>>>(xp, Bq, sc, partial);
    reduce_kernel<<<dim3(M_DIM * N_DIM / (256 * 8)), 256, 0, stream>>>(partial, out);
}